// Round 8
// baseline (388.712 us; speedup 1.0000x reference)
//
#include <hip/hip_runtime.h>

// BinarizeLinear: out[65536,1024] = x @ sign(W)^T + bias
// Round 8: deep-pipelined pure-bf16 GEMM (m201 mechanism: counted vmcnt +
// ring staging + per-phase barriers). Prepass 1 converts x fp32 -> bf16 into
// d_ws as frag-linear 16KB tile images; prepass 2 converts sign(W) -> bf16
// likewise (2 MB). GEMM: BM=BN=256, BK=32, 8 waves, LDS ring of 4 slots per
// operand (128 KB), both operands staged via global_load_lds (linear, images
// pre-baked frag-linear => all ds ops conflict-free). 2 phases per K-tile:
// {2 gload_lds (tile t+3) | 8 or 4 ds_read_b128 | setprio 16 MFMA | barrier},
// vmcnt(8) once per tile (3 tiles in flight, never drained to 0 mid-loop).
// Cascade: ws >= 131MB -> this path; ws >= 2MB -> R6 kernel; else inline.

typedef __bf16 bf16x8 __attribute__((ext_vector_type(8)));
typedef float  f32x4  __attribute__((ext_vector_type(4)));

constexpr int Mdim = 65536, Ndim = 1024, Kdim = 1024;
constexpr int BM = 256, BN = 256, BK = 32;
constexpr int NKT = Kdim / BK;                    // 32 K-tiles
constexpr int NWG = (Mdim / BM) * (Ndim / BN);    // 1024 blocks

typedef const __attribute__((address_space(1))) char ga_char;
typedef __attribute__((address_space(3))) char lds_char;
__device__ __forceinline__ void gload16(const void* g, void* l) {
    __builtin_amdgcn_global_load_lds((ga_char*)g, (lds_char*)l, 16, 0, 0);
}
__device__ __forceinline__ f32x4 mfma16(bf16x8 a, bf16x8 b, f32x4 c) {
    return __builtin_amdgcn_mfma_f32_16x16x32_bf16(a, b, c, 0, 0, 0);
}

// ---- prepass 1: x fp32 -> bf16 frag-linear images ----
// XB[id*8 + e], id = ((rowb*32 + kt)*16 + mb)*64 + lane
//   = bf16(x[rowb*256 + mb*16 + (lane&15)][kt*32 + (lane>>4)*8 + e])
__global__ __launch_bounds__(256)
void xprep_kernel(const float* __restrict__ X, __bf16* __restrict__ XB) {
    const int id   = blockIdx.x * 256 + threadIdx.x;   // 8388608 threads
    const int l    = id & 63;
    const int mb   = (id >> 6) & 15;
    const int kt   = (id >> 10) & 31;
    const int rowb = id >> 15;                          // 0..255
    const float* src = X + (size_t)(rowb * 256 + mb * 16 + (l & 15)) * Kdim
                         + kt * 32 + (l >> 4) * 8;
    f32x4 a = *(const f32x4*)src;
    f32x4 b = *(const f32x4*)(src + 4);
    bf16x8 o;
#pragma unroll
    for (int e = 0; e < 4; ++e) {
        o[e]     = (__bf16)a[e];
        o[e + 4] = (__bf16)b[e];
    }
    *(bf16x8*)(XB + (size_t)id * 8) = o;               // coalesced write
}

// ---- prepass 2: sign(W) -> bf16 frag-linear images (2 MB) ----
// WB[id*8 + e], id = ((colb*32 + kt)*16 + nb)*64 + lane
__global__ __launch_bounds__(256)
void wprep_kernel(const float* __restrict__ W, __bf16* __restrict__ WB) {
    const int id   = blockIdx.x * 256 + threadIdx.x;   // 131072 threads
    const int l    = id & 63;
    const int nb   = (id >> 6) & 15;
    const int kt   = (id >> 10) & 31;
    const int colb = id >> 15;                          // 0..3
    const float* src = W + (size_t)(colb * 256 + nb * 16 + (l & 15)) * Kdim
                         + kt * 32 + (l >> 4) * 8;
    f32x4 a = *(const f32x4*)src;
    f32x4 b = *(const f32x4*)(src + 4);
    bf16x8 o;
#pragma unroll
    for (int e = 0; e < 4; ++e) {
        o[e]     = (__bf16)(float)((a[e] > 0.f) - (a[e] < 0.f));
        o[e + 4] = (__bf16)(float)((b[e] > 0.f) - (b[e] < 0.f));
    }
    *(bf16x8*)(WB + (size_t)id * 8) = o;
}

// ---- main GEMM: ring-4, counted vmcnt, per-phase barriers ----
__global__ __launch_bounds__(512, 2)
void binlin_ring(const __bf16* __restrict__ XB, const __bf16* __restrict__ WB,
                 const float* __restrict__ bias, float* __restrict__ out)
{
    __shared__ __align__(16) __bf16 Al[4][8192];   // 4 ring slots x 16 KB
    __shared__ __align__(16) __bf16 Bl[4][8192];   // 4 ring slots x 16 KB

    // T1: bijective chunked XCD swizzle (1024 % 8 == 0), colb fastest
    const int swz  = (blockIdx.x & 7) * (NWG / 8) + (blockIdx.x >> 3);
    const int colb = swz & 3;
    const int rowb = swz >> 2;

    const int tid  = threadIdx.x;
    const int lane = tid & 63;
    const int wid  = tid >> 6;        // 0..7
    const int wr   = wid >> 2;        // M half (128 rows)
    const int wcn  = wid & 3;         // N quarter (64 cols)
    const int fr   = lane & 15;
    const int hq   = lane >> 4;

    const char* XAb = (const char*)(XB + (size_t)rowb * 32 * 8192);
    const char* WBb = (const char*)(WB + (size_t)colb * 32 * 8192);

    // stage(slot, ktc, half): each wave DMAs 1 KB of A and 1 KB of B.
    auto stage = [&](int slot, int ktc, int half) {
        const int off = half * 8192 + wid * 1024;
        gload16(XAb + ktc * 16384 + off + lane * 16, (char*)&Al[slot][0] + off);
        gload16(WBb + ktc * 16384 + off + lane * 16, (char*)&Bl[slot][0] + off);
    };

    // per-lane frag read bases (bytes within a slot); frag-linear -> each
    // wave's ds_read_b128 covers 1 KB contiguous (conflict-free).
    const int aoff = (wr * 8 * 64 + lane) * 16;   // + (ph*4 + i) * 1024
    const int boff = (wcn * 4 * 64 + lane) * 16;  // + j * 1024

    f32x4 acc[8][4] = {};

    // prologue: stage tiles 0,1,2 (12 gloads/wave); tile0 landed after
    // vmcnt(8) (tiles 1,2 = 8 loads stay in flight).
#pragma unroll
    for (int tt = 0; tt < 3; ++tt) { stage(tt, tt, 0); stage(tt, tt, 1); }
    asm volatile("s_waitcnt vmcnt(8)" ::: "memory");
    __builtin_amdgcn_s_barrier();

    for (int t = 0; t < NKT; ++t) {
        const int slotC = t & 3;
        const int slotS = (t + 3) & 3;                       // = slot(t-1), consumed
        const int ktc   = (t + 3 < NKT) ? t + 3 : NKT - 1;   // uniform clamp: ledger
        const char* A = (const char*)&Al[slotC][0];          //  stays exact at tail
        const char* B = (const char*)&Bl[slotC][0];
        bf16x8 af[4], bf[4];

        // -- phase 0: stage half 0 of tile t+3; compute m-rows 0-63 (x K=32)
        stage(slotS, ktc, 0);
#pragma unroll
        for (int j = 0; j < 4; ++j) bf[j] = *(const bf16x8*)(B + boff + j * 1024);
#pragma unroll
        for (int i = 0; i < 4; ++i) af[i] = *(const bf16x8*)(A + aoff + i * 1024);
        __builtin_amdgcn_s_setprio(1);
#pragma unroll
        for (int i = 0; i < 4; ++i)
#pragma unroll
            for (int j = 0; j < 4; ++j)
                acc[i][j] = mfma16(af[i], bf[j], acc[i][j]);
        __builtin_amdgcn_s_setprio(0);
        __builtin_amdgcn_s_barrier();

        // -- phase 1: stage half 1; compute m-rows 64-127 (B frags reused)
        stage(slotS, ktc, 1);
#pragma unroll
        for (int i = 0; i < 4; ++i) af[i] = *(const bf16x8*)(A + aoff + (4 + i) * 1024);
        __builtin_amdgcn_s_setprio(1);
#pragma unroll
        for (int i = 0; i < 4; ++i)
#pragma unroll
            for (int j = 0; j < 4; ++j)
                acc[4 + i][j] = mfma16(af[i], bf[j], acc[4 + i][j]);
        __builtin_amdgcn_s_setprio(0);
        // counted publish: all but newest 8 loads (tiles t+2, t+3) landed
        // => tile t+1 (staged at t-2) is resident for every wave.
        asm volatile("s_waitcnt vmcnt(8)" ::: "memory");
        __builtin_amdgcn_s_barrier();
    }

    // epilogue: C row = wr*128 + i*16 + hq*4 + r, col = wcn*64 + j*16 + fr
    const int orow = rowb * 256 + wr * 128 + hq * 4;
    const int ocol = colb * 256 + wcn * 64 + fr;
#pragma unroll
    for (int j = 0; j < 4; ++j) {
        const float bv = bias[ocol + j * 16];
#pragma unroll
        for (int i = 0; i < 8; ++i)
#pragma unroll
            for (int r = 0; r < 4; ++r)
                out[(size_t)(orow + i * 16 + r) * Ndim + (ocol + j * 16)] =
                    acc[i][j][r] + bv;
    }
}

// ---- middle path (2MB <= ws < 131MB): R6 kernel, proven 233 us ----
__global__ __launch_bounds__(512, 4)
void binlin128x256(const float* __restrict__ X, const __bf16* __restrict__ WS,
                   const float* __restrict__ bias, float* __restrict__ out)
{
    constexpr int mBM = 128, mBN = 256, mBK = 32;
    constexpr int mNWG = (Mdim / mBM) * (Ndim / mBN);
    __shared__ __align__(16) char Alc[2][mBM * 80];
    __shared__ __align__(16) __bf16 Bl[2][mBN * mBK];
    const int swz  = (blockIdx.x & 7) * (mNWG / 8) + (blockIdx.x >> 3);
    const int colb = swz & 3;
    const int rowb = swz >> 2;
    const int row0 = rowb * mBM;
    const int tid  = threadIdx.x;
    const int lane = tid & 63;
    const int wid  = tid >> 6;
    const int wr   = wid >> 2;
    const int wcn  = wid & 3;
    const int fr   = lane & 15;
    const int hq   = lane >> 4;
    const int a_r = tid >> 2;
    const int a_c = (tid & 3) * 8;
    const float* Xb = X + (size_t)(row0 + a_r) * Kdim + a_c;
    const __bf16* WSb = WS + (size_t)colb * 262144;
    f32x4 ra[2];
    auto GLA = [&](int kt) {
        const float* p = Xb + kt * mBK;
        ra[0] = *(const f32x4*)p;
        ra[1] = *(const f32x4*)(p + 4);
    };
    auto DSWA = [&](int buf) {
        bf16x8 v;
#pragma unroll
        for (int e = 0; e < 4; ++e) {
            v[e] = (__bf16)ra[0][e]; v[e + 4] = (__bf16)ra[1][e];
        }
        *(bf16x8*)(&Alc[buf][a_r * 80 + a_c * 2]) = v;
    };
    auto GLB = [&](int buf, int kt) {
        const __bf16* s = WSb + (size_t)kt * 8192 + wid * 1024 + lane * 8;
        gload16(s,       &Bl[buf][wid * 1024]);
        gload16(s + 512, &Bl[buf][wid * 1024 + 512]);
    };
    auto lda = [&](int buf, int i) -> bf16x8 {
        const int row = wr * 64 + i * 16 + fr;
        return *(const bf16x8*)(&Alc[buf][row * 80 + hq * 16]);
    };
    auto ldb = [&](int buf, int j) -> bf16x8 {
        return *(const bf16x8*)(&Bl[buf][(wcn * 4 + j) * 512 + lane * 8]);
    };
    f32x4 acc[4][4] = {};
    GLA(0); GLB(0, 0); DSWA(0);
    __syncthreads();
    int cur = 0;
    for (int t = 0; t < NKT; ++t) {
        const int nxt = cur ^ 1;
        const bool pre = (t + 1 < NKT);
        if (pre) { GLA(t + 1); GLB(nxt, t + 1); }
        bf16x8 af[4];
#pragma unroll
        for (int i = 0; i < 4; ++i) af[i] = lda(cur, i);
        __builtin_amdgcn_s_setprio(1);
#pragma unroll
        for (int j = 0; j < 4; ++j) {
            bf16x8 bfr = ldb(cur, j);
#pragma unroll
            for (int i = 0; i < 4; ++i)
                acc[i][j] = mfma16(af[i], bfr, acc[i][j]);
        }
        __builtin_amdgcn_s_setprio(0);
        if (pre) { DSWA(nxt); __syncthreads(); }
        cur = nxt;
    }
    const int orow = row0 + wr * 64 + hq * 4;
    const int ocol = colb * mBN + wcn * 64 + fr;
#pragma unroll
    for (int j = 0; j < 4; ++j) {
        const float bv = bias[ocol + j * 16];
#pragma unroll
        for (int i = 0; i < 4; ++i)
#pragma unroll
            for (int r = 0; r < 4; ++r)
                out[(size_t)(orow + i * 16 + r) * Ndim + (ocol + j * 16)] =
                    acc[i][j][r] + bv;
    }
}

// ---- last-resort fallback (ws < 2MB): reg-staged, inline sign ----
__global__ __launch_bounds__(256)
void binlin_fallback(const float* __restrict__ X, const float* __restrict__ Wf,
                     const float* __restrict__ bias, float* __restrict__ out)
{
    __shared__ __align__(16) __bf16 Al[2][128][32];
    __shared__ __align__(16) __bf16 Bl[2][128][32];
    constexpr int NT = Kdim / 32;
    const int swz  = (blockIdx.x & 7) * (4096 / 8) + (blockIdx.x >> 3);
    const int colb = swz & 7, rowb = swz >> 3;
    const int row0 = rowb * 128, col0 = colb * 128;
    const int tid = threadIdx.x, lane = tid & 63, wid = tid >> 6;
    const int wr = wid >> 1, wc = wid & 1;
    const int sr = tid >> 2, sc = (tid & 3) * 8;
    const float* Xb = X + (size_t)row0 * Kdim;
    const float* Wb = Wf + (size_t)col0 * Kdim;
    f32x4 ra[2][2], rb[2][2];
    auto GL = [&](int k0) {
#pragma unroll
        for (int p = 0; p < 2; ++p) {
            const float* sa = Xb + (size_t)(p * 64 + sr) * Kdim + k0 + sc;
            ra[p][0] = *(const f32x4*)sa; ra[p][1] = *(const f32x4*)(sa + 4);
            const float* sb = Wb + (size_t)(p * 64 + sr) * Kdim + k0 + sc;
            rb[p][0] = *(const f32x4*)sb; rb[p][1] = *(const f32x4*)(sb + 4);
        }
    };
    auto DSW = [&](int buf) {
#pragma unroll
        for (int p = 0; p < 2; ++p) {
            bf16x8 va, vb;
#pragma unroll
            for (int e = 0; e < 4; ++e) {
                va[e] = (__bf16)ra[p][0][e]; va[e + 4] = (__bf16)ra[p][1][e];
                float a = rb[p][0][e], b = rb[p][1][e];
                vb[e] = (__bf16)(float)((a > 0.f) - (a < 0.f));
                vb[e + 4] = (__bf16)(float)((b > 0.f) - (b < 0.f));
            }
            *(bf16x8*)&Al[buf][p * 64 + sr][sc] = va;
            *(bf16x8*)&Bl[buf][p * 64 + sr][sc] = vb;
        }
    };
    f32x4 acc[4][4] = {};
    const int fr = lane & 15, ks = (lane >> 4) * 8;
    auto COMP = [&](int buf) {
        bf16x8 af[4], bf[4];
#pragma unroll
        for (int i = 0; i < 4; ++i) af[i] = *(const bf16x8*)&Al[buf][wr * 64 + fr + i * 16][ks];
#pragma unroll
        for (int j = 0; j < 4; ++j) bf[j] = *(const bf16x8*)&Bl[buf][wc * 64 + fr + j * 16][ks];
#pragma unroll
        for (int i = 0; i < 4; ++i)
#pragma unroll
            for (int j = 0; j < 4; ++j)
                acc[i][j] = mfma16(af[i], bf[j], acc[i][j]);
    };
    GL(0); DSW(0); __syncthreads();
    int cur = 0;
    for (int t = 0; t < NT; ++t) {
        if (t + 1 < NT) GL((t + 1) * 32);
        COMP(cur);
        if (t + 1 < NT) { DSW(cur ^ 1); __syncthreads(); cur ^= 1; }
    }
    const int orow = row0 + wr * 64 + (lane >> 4) * 4;
    const int ocol = col0 + wc * 64 + fr;
#pragma unroll
    for (int j = 0; j < 4; ++j) {
        const float bv = bias[ocol + j * 16];
#pragma unroll
        for (int i = 0; i < 4; ++i)
#pragma unroll
            for (int r = 0; r < 4; ++r)
                out[(size_t)(orow + i * 16 + r) * Ndim + (ocol + j * 16)] = acc[i][j][r] + bv;
    }
}

extern "C" void kernel_launch(void* const* d_in, const int* in_sizes, int n_in,
                              void* d_out, int out_size, void* d_ws, size_t ws_size,
                              hipStream_t stream) {
    const float* x  = (const float*)d_in[0];
    const float* w  = (const float*)d_in[1];
    const float* b  = (const float*)d_in[2];
    float* out      = (float*)d_out;

    constexpr size_t WB_BYTES = (size_t)Ndim * Kdim * sizeof(__bf16);   // 2 MB
    constexpr size_t XB_BYTES = (size_t)Mdim * Kdim * sizeof(__bf16);   // 128 MB

    if (ws_size >= WB_BYTES + XB_BYTES) {
        __bf16* wb = (__bf16*)d_ws;
        __bf16* xb = (__bf16*)((char*)d_ws + WB_BYTES);
        wprep_kernel<<<dim3(512),   dim3(256), 0, stream>>>(w, wb);
        xprep_kernel<<<dim3(32768), dim3(256), 0, stream>>>(x, xb);
        binlin_ring<<<dim3(NWG), dim3(512), 0, stream>>>(xb, wb, b, out);
    } else if (ws_size >= WB_BYTES) {
        __bf16* wb = (__bf16*)d_ws;
        wprep_kernel<<<dim3(512), dim3(256), 0, stream>>>(w, wb);
        binlin128x256<<<dim3(2048), dim3(512), 0, stream>>>(x, wb, b, out);
    } else {
        binlin_fallback<<<dim3(4096), dim3(256), 0, stream>>>(x, w, b, out);
    }
}

// Round 10
// 275.727 us; speedup vs baseline: 1.4098x; 1.4098x over previous
//
#include <hip/hip_runtime.h>

// BinarizeLinear: out[65536,1024] = x @ sign(W)^T + bias
// Round 10: Round 9 (faithful 256^2 4-phase template, BK=64, 8 waves,
// counted vmcnt(8), two barriers per phase, frag-linear LDS) with the
// wprep grid fixed: 512 blocks (131072 threads), matching the 2048-group
// id decomposition. R9's grid=1024 read/wrote OOB -> core dump.

typedef __bf16 bf16x8 __attribute__((ext_vector_type(8)));
typedef float  f32x4  __attribute__((ext_vector_type(4)));

constexpr int Mdim = 65536, Ndim = 1024, Kdim = 1024;
constexpr int BM = 256, BN = 256, BK = 64;
constexpr int NKT = Kdim / BK;                    // 16 K-tiles
constexpr int NWG = (Mdim / BM) * (Ndim / BN);    // 1024 blocks

typedef const __attribute__((address_space(1))) char ga_char;
typedef __attribute__((address_space(3))) char lds_char;
__device__ __forceinline__ void gload16(const void* g, void* l) {
    __builtin_amdgcn_global_load_lds((ga_char*)g, (lds_char*)l, 16, 0, 0);
}
__device__ __forceinline__ f32x4 mfma16(bf16x8 a, bf16x8 b, f32x4 c) {
    return __builtin_amdgcn_mfma_f32_16x16x32_bf16(a, b, c, 0, 0, 0);
}

// ---- prepass: sign(W) -> bf16 frag-linear image, 2 MB ----
// id = (colb*512 + kt*32 + half*16 + ks*8 + nb)*64 + lane   (2048 groups)
// WB[id*8+e] = sign(W[colb*256 + half*128 + nb*16 + (lane&15)]
//                    [kt*64 + ks*32 + (lane>>4)*8 + e])
__global__ __launch_bounds__(256)
void wprep_kernel(const float* __restrict__ W, __bf16* __restrict__ WB) {
    const int id   = blockIdx.x * 256 + threadIdx.x;   // 131072 threads
    const int lane = id & 63;
    const int g    = id >> 6;
    const int nb   = g & 7;
    const int ks   = (g >> 3) & 1;
    const int half = (g >> 4) & 1;
    const int kt   = (g >> 5) & 15;
    const int colb = g >> 9;                            // 0..3
    const int row  = colb * 256 + half * 128 + nb * 16 + (lane & 15);
    const int col  = kt * 64 + ks * 32 + (lane >> 4) * 8;
    const float* src = W + (size_t)row * Kdim + col;
    f32x4 a = *(const f32x4*)src;
    f32x4 b = *(const f32x4*)(src + 4);
    bf16x8 o;
#pragma unroll
    for (int e = 0; e < 4; ++e) {
        o[e]     = (__bf16)(float)((a[e] > 0.f) - (a[e] < 0.f));
        o[e + 4] = (__bf16)(float)((b[e] > 0.f) - (b[e] < 0.f));
    }
    *(bf16x8*)(WB + (size_t)id * 8) = o;
}

// ---- main GEMM: the 4-phase-per-K-tile template ----
__global__ __launch_bounds__(512, 2)
void binlin_t8(const float* __restrict__ X, const __bf16* __restrict__ WB,
               const float* __restrict__ bias, float* __restrict__ out)
{
    // frag-linear LDS: A [mh][ks][mb0..7][lane*8], B [half][ks][nb0..7][lane*8]
    __shared__ __align__(16) __bf16 Al[2][16384];   // 2 x 32 KB
    __shared__ __align__(16) __bf16 Bl[2][16384];   // 2 x 32 KB

    // T1 bijective chunked XCD swizzle (1024 % 8 == 0), colb fastest
    const int swz  = (blockIdx.x & 7) * (NWG / 8) + (blockIdx.x >> 3);
    const int colb = swz & 3;
    const int rowb = swz >> 2;
    const int row0 = rowb * BM;

    const int tid  = threadIdx.x;
    const int lane = tid & 63;
    const int wid  = tid >> 6;       // 0..7
    const int wr   = wid >> 2;       // M half (128 rows)
    const int wcn  = wid & 3;        // N quarter (64 cols)
    const int fr   = lane & 15;
    const int hq   = lane >> 4;

    // A staging map: thread -> (row rl = tid>>2 within half, 16 floats @ fc*16)
    const int rl   = tid >> 2;       // 0..127
    const int fc   = tid & 3;        // 0..3
    const int mb_s = rl >> 4, rr_s = rl & 15;
    const int s_s  = fc >> 1,  kh_s = fc & 1;
    const float* Xr0 = X + (size_t)(row0 + rl) * Kdim + fc * 16;   // half 0
    const float* Xr1 = Xr0 + (size_t)128 * Kdim;                   // half 1

    const __bf16* WBb = WB + (size_t)colb * 262144;

    f32x4 rA0[4], rA1[4];            // depth-2 A half-tile reg sets

    auto GLA0 = [&](int kt) {
        const float* p = Xr0 + kt * BK;
#pragma unroll
        for (int q = 0; q < 4; ++q) rA0[q] = *(const f32x4*)(p + q * 4);
    };
    auto GLA1 = [&](int kt) {
        const float* p = Xr1 + kt * BK;
#pragma unroll
        for (int q = 0; q < 4; ++q) rA1[q] = *(const f32x4*)(p + q * 4);
    };
    // fused cvt + 2x ds_write_b128 into frag-linear A
    auto DSW = [&](int buf, int h) {
        const f32x4* r = h ? rA1 : rA0;
        const int base = h * 8192 + s_s * 4096 + mb_s * 512;
#pragma unroll
        for (int jj = 0; jj < 2; ++jj) {
            bf16x8 v;
#pragma unroll
            for (int e = 0; e < 4; ++e) {
                v[e]     = (__bf16)r[jj * 2][e];
                v[e + 4] = (__bf16)r[jj * 2 + 1][e];
            }
            *(bf16x8*)&Al[buf][base + ((kh_s * 2 + jj) * 16 + rr_s) * 8] = v;
        }
    };
    // stage one B half-tile (16 KB) via 2 gload16 rounds (linear copy)
    auto GLB = [&](int buf, int kt, int half) {
        const __bf16* img = WBb + (size_t)(kt * 2 + half) * 8192;
#pragma unroll
        for (int r = 0; r < 2; ++r) {
            const int chunk = r * 8 + wid;
            gload16(img + chunk * 512 + lane * 8,
                    &Bl[buf][half * 8192 + chunk * 512]);
        }
    };

    auto lda = [&](int buf, int i, int ks) -> bf16x8 {
        return *(const bf16x8*)&Al[buf][wr * 8192 + ks * 4096 + i * 512 + lane * 8];
    };
    auto ldb = [&](int buf, int j, int ks) -> bf16x8 {
        const int nbg = wcn * 4 + j;
        return *(const bf16x8*)&Bl[buf][(nbg >> 3) * 8192 + (ks * 8 + (nbg & 7)) * 512 + lane * 8];
    };

#define PHASE_SYNC() do { __builtin_amdgcn_s_barrier();                        \
    asm volatile("s_waitcnt lgkmcnt(0)" ::: "memory");                         \
    __builtin_amdgcn_sched_barrier(0); } while (0)

    f32x4 acc[8][4] = {};
    bf16x8 af[4], bf[4];

    // prologue: tile0 fully staged into buf0; tile1 A regs loaded
    GLB(0, 0, 0); GLB(0, 0, 1);
    GLA0(0); GLA1(0);
    DSW(0, 0); DSW(0, 1);
    GLA0(1); GLA1(1);                // tile1 regs (re-drained by syncthreads)
    __syncthreads();

    for (int t = 0; t < NKT; ++t) {
        const int c  = t & 1;
        const int n  = c ^ 1;
        const int tS = (t + 1 < NKT) ? t + 1 : NKT - 1;   // uniform clamps:
        const int tA = (t + 2 < NKT) ? t + 2 : NKT - 1;   // ledger stays exact

        // ---- PH0: frags (i0-3, ks0) + B frags ks0; stage B-half0(t+1); A-h0 write
#pragma unroll
        for (int j = 0; j < 4; ++j) bf[j] = ldb(c, j, 0);
#pragma unroll
        for (int i = 0; i < 4; ++i) af[i] = lda(c, i, 0);
        GLB(n, tS, 0);
        DSW(n, 0);                    // rA0 = tile t+1 half0 (loaded iter t-1)
        PHASE_SYNC();
        __builtin_amdgcn_s_setprio(1);
#pragma unroll
        for (int i = 0; i < 4; ++i)
#pragma unroll
            for (int j = 0; j < 4; ++j)
                acc[i][j] = mfma16(af[i], bf[j], acc[i][j]);
        __builtin_amdgcn_s_setprio(0);
        __builtin_amdgcn_s_barrier();

        // ---- PH1: frags (i4-7, ks0); stage B-half1(t+1)
#pragma unroll
        for (int i = 0; i < 4; ++i) af[i] = lda(c, 4 + i, 0);
        GLB(n, tS, 1);
        PHASE_SYNC();
        __builtin_amdgcn_s_setprio(1);
#pragma unroll
        for (int i = 0; i < 4; ++i)
#pragma unroll
            for (int j = 0; j < 4; ++j)
                acc[4 + i][j] = mfma16(af[i], bf[j], acc[4 + i][j]);
        __builtin_amdgcn_s_setprio(0);
        __builtin_amdgcn_s_barrier();

        // ---- PH2: frags (i0-3, ks1) + B frags ks1; load A-h0(t+2); A-h1 write
#pragma unroll
        for (int j = 0; j < 4; ++j) bf[j] = ldb(c, j, 1);
#pragma unroll
        for (int i = 0; i < 4; ++i) af[i] = lda(c, i, 1);
        GLA0(tA);                     // overwrites rA0 (consumed at PH0)
        DSW(n, 1);                    // rA1 = tile t+1 half1 (loaded iter t-1)
        PHASE_SYNC();
        __builtin_amdgcn_s_setprio(1);
#pragma unroll
        for (int i = 0; i < 4; ++i)
#pragma unroll
            for (int j = 0; j < 4; ++j)
                acc[i][j] = mfma16(af[i], bf[j], acc[i][j]);
        __builtin_amdgcn_s_setprio(0);
        __builtin_amdgcn_s_barrier();

        // ---- PH3: frags (i4-7, ks1); load A-h1(t+2); counted publish
#pragma unroll
        for (int i = 0; i < 4; ++i) af[i] = lda(c, 4 + i, 1);
        GLA1(tA);                     // overwrites rA1 (consumed at PH2)
        PHASE_SYNC();
        __builtin_amdgcn_s_setprio(1);
#pragma unroll
        for (int i = 0; i < 4; ++i)
#pragma unroll
            for (int j = 0; j < 4; ++j)
                acc[4 + i][j] = mfma16(af[i], bf[j], acc[4 + i][j]);
        __builtin_amdgcn_s_setprio(0);
        // vmem order this iter: [2 B][2 B][4 A][4 A] -> vmcnt(8) == B landed,
        // 8 A loads (tile t+2) stay in flight. Never drains to 0 mid-loop.
        asm volatile("s_waitcnt vmcnt(8)" ::: "memory");
        __builtin_amdgcn_s_barrier();
    }
#undef PHASE_SYNC

    // epilogue: C row = rowb*256 + wr*128 + i*16 + hq*4 + r, col = j*16 + fr
    const int orow = row0 + wr * 128 + hq * 4;
    const int ocol = colb * 256 + wcn * 64 + fr;
#pragma unroll
    for (int j = 0; j < 4; ++j) {
        const float bv = bias[ocol + j * 16];
#pragma unroll
        for (int i = 0; i < 8; ++i)
#pragma unroll
            for (int r = 0; r < 4; ++r)
                out[(size_t)(orow + i * 16 + r) * Ndim + (ocol + j * 16)] =
                    acc[i][j][r] + bv;
    }
}

// ---- fallback (ws < 2MB): reg-staged 128x128, inline sign ----
__global__ __launch_bounds__(256)
void binlin_fallback(const float* __restrict__ X, const float* __restrict__ Wf,
                     const float* __restrict__ bias, float* __restrict__ out)
{
    __shared__ __align__(16) __bf16 Al[2][128][32];
    __shared__ __align__(16) __bf16 Bl[2][128][32];
    constexpr int NT = Kdim / 32;
    const int swz  = (blockIdx.x & 7) * (4096 / 8) + (blockIdx.x >> 3);
    const int colb = swz & 7, rowb = swz >> 3;
    const int row0 = rowb * 128, col0 = colb * 128;
    const int tid = threadIdx.x, lane = tid & 63, wid = tid >> 6;
    const int wr = wid >> 1, wc = wid & 1;
    const int sr = tid >> 2, sc = (tid & 3) * 8;
    const float* Xb = X + (size_t)row0 * Kdim;
    const float* Wb = Wf + (size_t)col0 * Kdim;
    f32x4 ra[2][2], rb[2][2];
    auto GL = [&](int k0) {
#pragma unroll
        for (int p = 0; p < 2; ++p) {
            const float* sa = Xb + (size_t)(p * 64 + sr) * Kdim + k0 + sc;
            ra[p][0] = *(const f32x4*)sa; ra[p][1] = *(const f32x4*)(sa + 4);
            const float* sb = Wb + (size_t)(p * 64 + sr) * Kdim + k0 + sc;
            rb[p][0] = *(const f32x4*)sb; rb[p][1] = *(const f32x4*)(sb + 4);
        }
    };
    auto DSW = [&](int buf) {
#pragma unroll
        for (int p = 0; p < 2; ++p) {
            bf16x8 va, vb;
#pragma unroll
            for (int e = 0; e < 4; ++e) {
                va[e] = (__bf16)ra[p][0][e]; va[e + 4] = (__bf16)ra[p][1][e];
                float a = rb[p][0][e], b = rb[p][1][e];
                vb[e] = (__bf16)(float)((a > 0.f) - (a < 0.f));
                vb[e + 4] = (__bf16)(float)((b > 0.f) - (b < 0.f));
            }
            *(bf16x8*)&Al[buf][p * 64 + sr][sc] = va;
            *(bf16x8*)&Bl[buf][p * 64 + sr][sc] = vb;
        }
    };
    f32x4 acc[4][4] = {};
    const int fr = lane & 15, ks = (lane >> 4) * 8;
    auto COMP = [&](int buf) {
        bf16x8 af[4], bf[4];
#pragma unroll
        for (int i = 0; i < 4; ++i) af[i] = *(const bf16x8*)&Al[buf][wr * 64 + fr + i * 16][ks];
#pragma unroll
        for (int j = 0; j < 4; ++j) bf[j] = *(const bf16x8*)&Bl[buf][wc * 64 + fr + j * 16][ks];
#pragma unroll
        for (int i = 0; i < 4; ++i)
#pragma unroll
            for (int j = 0; j < 4; ++j)
                acc[i][j] = mfma16(af[i], bf[j], acc[i][j]);
    };
    GL(0); DSW(0); __syncthreads();
    int cur = 0;
    for (int t = 0; t < NT; ++t) {
        if (t + 1 < NT) GL((t + 1) * 32);
        COMP(cur);
        if (t + 1 < NT) { DSW(cur ^ 1); __syncthreads(); cur ^= 1; }
    }
    const int orow = row0 + wr * 64 + (lane >> 4) * 4;
    const int ocol = col0 + wc * 64 + fr;
#pragma unroll
    for (int j = 0; j < 4; ++j) {
        const float bv = bias[ocol + j * 16];
#pragma unroll
        for (int i = 0; i < 4; ++i)
#pragma unroll
            for (int r = 0; r < 4; ++r)
                out[(size_t)(orow + i * 16 + r) * Ndim + (ocol + j * 16)] = acc[i][j][r] + bv;
    }
}

extern "C" void kernel_launch(void* const* d_in, const int* in_sizes, int n_in,
                              void* d_out, int out_size, void* d_ws, size_t ws_size,
                              hipStream_t stream) {
    const float* x  = (const float*)d_in[0];
    const float* w  = (const float*)d_in[1];
    const float* b  = (const float*)d_in[2];
    float* out      = (float*)d_out;

    constexpr size_t WB_BYTES = (size_t)Ndim * Kdim * sizeof(__bf16);   // 2 MB

    if (ws_size >= WB_BYTES) {
        __bf16* wb = (__bf16*)d_ws;
        wprep_kernel<<<dim3(512), dim3(256), 0, stream>>>(w, wb);   // FIXED: 512
        binlin_t8<<<dim3(NWG), dim3(512), 0, stream>>>(x, wb, b, out);
    } else {
        binlin_fallback<<<dim3(4096), dim3(256), 0, stream>>>(x, w, b, out);
    }
}